// Round 3
// baseline (384.485 us; speedup 1.0000x reference)
//
#include <hip/hip_runtime.h>

#define HS   1024
#define SEQ  512
#define NBAT 64
#define INSZ 8
#define NM   4
#define DD   12

#define ALPHA 0.1f
#define OMA   0.9f
#define SCL   (500.0f/1024.0f)
#define AS    (ALPHA*SCL)

// exp(2h) evaluated as exp2(GS*h) when native exp2 builtin exists, else expf(2h).
// All scaled states (A, B, Yg) carry the SAME GS factor, fixed at compile time.
#if __has_builtin(__builtin_amdgcn_exp2f)
  #define GS 2.8853900817779268f      /* 2*log2(e) */
  #define EXPG(v) __builtin_amdgcn_exp2f(v)
#else
  #define GS 2.0f
  #define EXPG(v) __expf(v)
#endif

typedef float f2 __attribute__((ext_vector_type(2)));
__device__ __forceinline__ f2 mk2(float a, float b){ f2 r; r.x=a; r.y=b; return r; }
__device__ __forceinline__ f2 splat2(float a){ return mk2(a,a); }
#if __has_builtin(__builtin_elementwise_fma)
__device__ __forceinline__ f2 fma2(f2 a, f2 b, f2 c){ return __builtin_elementwise_fma(a,b,c); }
#else
__device__ __forceinline__ f2 fma2(f2 a, f2 b, f2 c){
  f2 r; r.x=fmaf(a.x,b.x,c.x); r.y=fmaf(a.y,b.y,c.y); return r; }
#endif

// DPP-based add: v += dpp_move(v). old=0 so masked/invalid lanes add 0.
#define DPP_ADD(v, ctrl, rmask, bmask) \
  v += __int_as_float(__builtin_amdgcn_update_dpp(0, __float_as_int(v), ctrl, rmask, bmask, true))

// Canonical gfx9 wave64 sum. Lane 63 holds the full 64-lane total afterwards.
__device__ __forceinline__ void wave64_sum2(float &a, float &b){
  DPP_ADD(a, 0x111, 0xf, 0xf); DPP_ADD(b, 0x111, 0xf, 0xf);  // row_shr:1
  DPP_ADD(a, 0x112, 0xf, 0xf); DPP_ADD(b, 0x112, 0xf, 0xf);  // row_shr:2
  DPP_ADD(a, 0x114, 0xf, 0xe); DPP_ADD(b, 0x114, 0xf, 0xe);  // row_shr:4
  DPP_ADD(a, 0x118, 0xf, 0xc); DPP_ADD(b, 0x118, 0xf, 0xc);  // row_shr:8
  DPP_ADD(a, 0x142, 0xa, 0xf); DPP_ADD(b, 0x142, 0xa, 0xf);  // row_bcast:15
  DPP_ADD(a, 0x143, 0xc, 0xf); DPP_ADD(b, 0x143, 0xc, 0xf);  // row_bcast:31
}
#define RD63(v) __int_as_float(__builtin_amdgcn_readlane(__float_as_int(v), 63))

// mixed[e] for unit i, e in [E0,E1)
template<int E0, int E1>
__device__ __forceinline__ void mix_unit(int i, const float* __restrict__ eps,
                                         const float* __restrict__ means,
                                         const float* __restrict__ tril,
                                         const float* w, float* outm){
  float ep[NM][DD];
  #pragma unroll
  for (int k=0;k<NM;k++){
    const float4* p = (const float4*)(eps + (size_t)(k*HS + i)*DD);
    float4 r0=p[0], r1=p[1], r2=p[2];
    ep[k][0]=r0.x; ep[k][1]=r0.y; ep[k][2]=r0.z; ep[k][3]=r0.w;
    ep[k][4]=r1.x; ep[k][5]=r1.y; ep[k][6]=r1.z; ep[k][7]=r1.w;
    ep[k][8]=r2.x; ep[k][9]=r2.y; ep[k][10]=r2.z; ep[k][11]=r2.w;
  }
  #pragma unroll
  for (int e=E0;e<E1;e++){
    float a = 0.f;
    #pragma unroll
    for (int k=0;k<NM;k++){
      float se = means[k*DD+e];
      #pragma unroll
      for (int d=0; d<e; d++) se = fmaf(ep[k][d], tril[(k*DD+e)*DD+d], se);
      float dg = fabsf(tril[(k*DD+e)*DD+e] - 1e-12f) + 1e-12f;
      se = fmaf(ep[k][e], dg, se);
      a = fmaf(w[k], se, a);
    }
    outm[e-E0] = a;
  }
}

// Single-wave-per-batch serial scan. Entire steady state lives in registers:
// h_i(t) = m0_i*A(t) + m1_i*B(t) + P_i(t), P = Iv . Yg, Yg = 8-dim EMA of x.
// The 64-fma2 Iv.Yg block is independent of the serial u-chain and fills the
// wave's issue slots while the trans pipe (16 exp + 16 rcp) is busy.
__global__ __launch_bounds__(64,1)
void rnn_scan(const float* __restrict__ x, const float* __restrict__ eps,
              const float* __restrict__ means, const float* __restrict__ tril,
              const float* __restrict__ mw, float* __restrict__ out)
{
  const int b    = blockIdx.x;
  const int lane = threadIdx.x;           // 64 threads = 1 wave, 16 units/lane

  __shared__ float xs[SEQ*INSZ];                // 16 KB
  __shared__ __align__(16) float outb[SEQ*10];  // 20 KB

  // stage x[b] first so the loads fly during parameter preprocessing
  { const float4* xp=(const float4*)(x + (size_t)b*SEQ*INSZ);
    float4* xd=(float4*)xs;
    for (int idx=lane; idx<SEQ*INSZ/4; idx+=64) xd[idx]=xp[idx]; }

  float w[NM];
  { float s=0.f;
    #pragma unroll
    for (int k=0;k<NM;k++){ w[k]=fmaxf(mw[k],1e-6f); s+=w[k]; }
    float inv=1.0f/s;
    #pragma unroll
    for (int k=0;k<NM;k++) w[k]*=inv; }

  // params for unit pairs p: units 16*lane+2p, 16*lane+2p+1
  f2 m0v[8], m1v[8], n0v[8], n1v[8], Iv[8][8];
  float sn0=0.f, sn1=0.f;
  #pragma unroll
  for (int p=0;p<8;p++){
    float mA[DD], mB[DD];
    mix_unit<0,12>(16*lane+2*p,   eps, means, tril, w, mA);
    mix_unit<0,12>(16*lane+2*p+1, eps, means, tril, w, mB);
    m0v[p]=mk2(mA[0],mB[0]); m1v[p]=mk2(mA[1],mB[1]);
    sn0 += mA[2]+mB[2];      sn1 += mA[3]+mB[3];
    n0v[p]=mk2(-2.f*mA[2], -2.f*mB[2]);
    n1v[p]=mk2(-2.f*mA[3], -2.f*mB[3]);
    #pragma unroll
    for (int e=0;e<8;e++) Iv[p][e]=mk2(mA[4+e], mB[4+e]);
  }
  wave64_sum2(sn0, sn1);
  const float N0 = RD63(sn0), N1 = RD63(sn1);

  __syncthreads();   // single wave: just drains the xs stores

  const float AG = GS*ALPHA;
  const float CA = GS*AS;
  float A=0.f, Bst=0.f, o=0.f;
  float Yg[8];
  #pragma unroll
  for (int e=0;e<8;e++) Yg[e]=0.f;
  f2 gI[8];                                // Iv . Yg for the CURRENT step
  #pragma unroll
  for (int p=0;p<8;p++) gI[p]=mk2(0.f,0.f);

  const float4* xs4 = (const float4*)xs;

  #pragma unroll 2
  for (int t=0;t<SEQ;t++){
    // fold in the rank-2 recurrent term (only part needing A(t),B(t))
    f2 g[8];
    { f2 A2=splat2(A), B2=splat2(Bst);
      #pragma unroll
      for (int p=0;p<8;p++){
        f2 gg = fma2(m0v[p], A2, gI[p]);
        g[p]  = fma2(m1v[p], B2, gg);
      } }

    // tanh core: r = 1/(e^{2h}+1); u = N - 2*sum(n*r)  (n0v/n1v carry -2n)
    f2 rr[8];
    #pragma unroll
    for (int p=0;p<8;p++){
      f2 ex = mk2(EXPG(g[p].x), EXPG(g[p].y));
      f2 dd = mk2(ex.x+1.f, ex.y+1.f);
      rr[p] = mk2(__builtin_amdgcn_rcpf(dd.x), __builtin_amdgcn_rcpf(dd.y));
    }
    f2 ua=mk2(0.f,0.f), ub=mk2(0.f,0.f), uc=mk2(0.f,0.f), ud=mk2(0.f,0.f);
    #pragma unroll
    for (int p=0;p<4;p++){ ua=fma2(rr[p],n0v[p],ua); ub=fma2(rr[p],n1v[p],ub); }
    #pragma unroll
    for (int p=4;p<8;p++){ uc=fma2(rr[p],n0v[p],uc); ud=fma2(rr[p],n1v[p],ud); }
    float u0=(ua.x+ua.y)+(uc.x+uc.y);
    float u1=(ub.x+ub.y)+(ud.x+ud.y);

    // independent of the u-chain: advance Yg with x_t, rebuild gI for t+1.
    // Scheduler interleaves these 72 pk-fmas into the trans-pipe gaps above.
    { float4 xa=xs4[t*2], xb=xs4[t*2+1];
      Yg[0]=fmaf(OMA,Yg[0],AG*xa.x); Yg[1]=fmaf(OMA,Yg[1],AG*xa.y);
      Yg[2]=fmaf(OMA,Yg[2],AG*xa.z); Yg[3]=fmaf(OMA,Yg[3],AG*xa.w);
      Yg[4]=fmaf(OMA,Yg[4],AG*xb.x); Yg[5]=fmaf(OMA,Yg[5],AG*xb.y);
      Yg[6]=fmaf(OMA,Yg[6],AG*xb.z); Yg[7]=fmaf(OMA,Yg[7],AG*xb.w);
      #pragma unroll
      for (int p=0;p<8;p++){
        f2 a = Iv[p][0]*splat2(Yg[0]);
        #pragma unroll
        for (int e=1;e<8;e++) a = fma2(Iv[p][e], splat2(Yg[e]), a);
        gI[p]=a;
      } }

    wave64_sum2(u0,u1);                  // pure-DPP, lane 63 has totals
    float U0 = N0 + RD63(u0);
    float U1 = N1 + RD63(u1);
    A   = fmaf(CA, U0, OMA*A);
    Bst = fmaf(CA, U1, OMA*Bst);

    // o_t = pinv(span) @ h_t exactly (h lives in col(span), pinv@span = I_10)
    if (lane<10){
      float add = lane==0 ? SCL*U0 : lane==1 ? SCL*U1 : xs[t*8+lane-2];
      o = fmaf(OMA, o, ALPHA*add);
      outb[t*10+lane]=o;
    }
  }

  __syncthreads();
  const float4* ob4 = (const float4*)outb;
  float4* o4 = (float4*)out + (size_t)b*(SEQ*10/4);
  for (int idx=lane; idx<SEQ*10/4; idx+=64) o4[idx]=ob4[idx];
}

extern "C" void kernel_launch(void* const* d_in, const int* in_sizes, int n_in,
                              void* d_out, int out_size, void* d_ws, size_t ws_size,
                              hipStream_t stream) {
  const float* x     = (const float*)d_in[0];  // (64,512,8)
  const float* eps   = (const float*)d_in[1];  // (4,1024,12)
  const float* means = (const float*)d_in[2];  // (4,12)
  const float* tril  = (const float*)d_in[3];  // (4,12,12)
  const float* mw    = (const float*)d_in[4];  // (4,)
  float* out = (float*)d_out;                  // (64,512,10) fp32

  rnn_scan<<<NBAT, 64, 0, stream>>>(x, eps, means, tril, mw, out);
}